// Round 12
// baseline (153.062 us; speedup 1.0000x reference)
//
#include <hip/hip_runtime.h>

#define NF 128
#define NCHUNK 32          // edge chunks
#define NRH 4              // hist node-range splits (LDS 25KB)
#define NRF 8              // fill node-range splits (LDS 12.5KB)
#define NNW_MAX 25088      // max packed u16-pair words; n_nodes <= 50176
#define RWH_MAX ((NNW_MAX + NRH - 1) / NRH)
#define RWF_MAX ((NNW_MAX + NRF - 1) / NRF)
#define GG_NODES 32        // nodes per fused gather+gemm block (fine-grained)

typedef __attribute__((ext_vector_type(8))) short short8;   // 8 x bf16
typedef __attribute__((ext_vector_type(4))) float f32x4;
typedef unsigned int uint;
typedef unsigned short ushort;

__device__ __forceinline__ ushort f2bf(float f) {
    uint u = __float_as_uint(f);
    uint r = (u + 0x7fffu + ((u >> 16) & 1u)) >> 16;
    return (ushort)r;
}
__device__ __forceinline__ float bflo(uint v) { return __uint_as_float(v << 16); }
__device__ __forceinline__ float bfhi(uint v) { return __uint_as_float(v & 0xffff0000u); }

// ---------------------------------------------------------------------------
// K1: range-split LDS degree histograms (no global atomics).
// ---------------------------------------------------------------------------
__global__ __launch_bounds__(512) void hist_kernel(const int* __restrict__ src,
                                                   const int* __restrict__ dst,
                                                   uint* __restrict__ partial_in,
                                                   uint* __restrict__ partial_out,
                                                   int n_edges, int nwords, int epb, int rw) {
    __shared__ uint h[RWH_MAX];
    int wbeg = blockIdx.z * rw;
    int wend = min(wbeg + rw, nwords);
    int nw = wend - wbeg;
    for (int w = threadIdx.x; w < nw; w += 512) h[w] = 0;
    __syncthreads();
    const int* idx = blockIdx.y ? src : dst;
    int ebeg = blockIdx.x * epb;
    int eend = min(ebeg + epb, n_edges);
    int nodelo = wbeg * 2, nodehi = wend * 2;
    for (int e = ebeg + (int)threadIdx.x; e < eend; e += 512) {
        int node = idx[e];
        if (node >= nodelo && node < nodehi)
            atomicAdd(&h[(node >> 1) - wbeg], 1u << ((node & 1) * 16));
    }
    __syncthreads();
    uint* p = (blockIdx.y ? partial_out : partial_in) + (size_t)blockIdx.x * nwords + wbeg;
    for (int w = threadIdx.x; w < nw; w += 512) p[w] = h[w];
}

// ---------------------------------------------------------------------------
// K2 (FUSED dnr+prep): phase A: partials -> deg_in[], norm[] (also in LDS),
// rel[c][w] in-place, bsum[b]. phase B: coalesced bf16 conversion of this
// block's 1024 feature rows using LDS norms. One kernel, one launch.
// ---------------------------------------------------------------------------
__global__ __launch_bounds__(512) void dnrp_kernel(const uint* __restrict__ partial_in,
                                                   uint* __restrict__ partial_out,
                                                   int* __restrict__ deg_in,
                                                   float* __restrict__ norm,
                                                   int* __restrict__ bsum,
                                                   const float* __restrict__ feat,
                                                   uint* __restrict__ featn,
                                                   int nwords, int n, int total) {
    __shared__ float nrm[1024];
    __shared__ int wsum[8];
    int tid = (int)threadIdx.x;
    int w = blockIdx.x * 512 + tid;
    uint si0 = 0, si1 = 0, so0 = 0, so1 = 0;
    if (w < nwords) {
        for (int c = 0; c < NCHUNK; ++c) {
            uint vi = partial_in[(size_t)c * nwords + w];
            uint vo = partial_out[(size_t)c * nwords + w];
            partial_out[(size_t)c * nwords + w] = si0 | (si1 << 16);   // rel
            si0 += vi & 0xffffu; si1 += vi >> 16;
            so0 += vo & 0xffffu; so1 += vo >> 16;
        }
        int n0 = 2 * w, n1 = 2 * w + 1;
        {
            uint di = si0 < 1u ? 1u : si0, dv = so0 < 1u ? 1u : so0;
            float nv = 1.0f / sqrtf((float)di * (float)dv);
            deg_in[n0] = (int)si0;
            norm[n0] = nv;
            nrm[2 * tid] = nv;
        }
        {
            uint di = si1 < 1u ? 1u : si1, dv = so1 < 1u ? 1u : so1;
            float nv = 1.0f / sqrtf((float)di * (float)dv);
            if (n1 < n) { deg_in[n1] = (int)si1; norm[n1] = nv; }
            nrm[2 * tid + 1] = nv;
        }
    } else {
        nrm[2 * tid] = 0.0f;
        nrm[2 * tid + 1] = 0.0f;
    }
    int v = (int)(si0 + si1);
#pragma unroll
    for (int off = 32; off >= 1; off >>= 1) v += __shfl_down(v, off, 64);
    int wave = tid >> 6, lane = tid & 63;
    if (lane == 0) wsum[wave] = v;
    __syncthreads();                       // nrm[] + wsum[] visible
    if (tid == 0) {
        int s = 0;
#pragma unroll
        for (int k = 0; k < 8; ++k) s += wsum[k];
        bsum[blockIdx.x] = s;
    }
    // phase B: convert this block's 1024 nodes (65536 u32 pairs), coalesced
    int base = blockIdx.x * 65536;
    for (int k = 0; k < 128; ++k) {
        int off = k * 512 + tid;
        int idx = base + off;
        if (idx < total) {
            float nv = nrm[off >> 6];
            float2 fv = ((const float2*)feat)[idx];
            featn[idx] = (uint)f2bf(fv.x * nv) | ((uint)f2bf(fv.y * nv) << 16);
        }
    }
}

// ---------------------------------------------------------------------------
// K3: scan_final2 + wt conversion (blocks >= nb do W^T bf16 packing)
// ---------------------------------------------------------------------------
__global__ __launch_bounds__(1024) void scan2wt_kernel(const int* __restrict__ deg,
                                                       const int* __restrict__ bsum,
                                                       int* __restrict__ start,
                                                       int n, int nb,
                                                       const float* __restrict__ W,
                                                       uint* __restrict__ wt) {
    if ((int)blockIdx.x >= nb) {
        int idx = ((int)blockIdx.x - nb) * 1024 + (int)threadIdx.x;
        if (idx < NF * NF / 2) {
            int nrow = idx >> 6;
            int k2 = idx & 63;
            float a = W[(2 * k2) * NF + nrow];
            float b = W[(2 * k2 + 1) * NF + nrow];
            wt[idx] = (uint)f2bf(a) | ((uint)f2bf(b) << 16);
        }
        return;
    }
    __shared__ int ws[16];
    __shared__ int wo[16];
    __shared__ int bpre_s;
    int i = blockIdx.x * 1024 + (int)threadIdx.x;
    int v = (i < n) ? deg[i] : 0;
    int lane = threadIdx.x & 63, wv = threadIdx.x >> 6;
    int incl = v;
#pragma unroll
    for (int off = 1; off < 64; off <<= 1) {
        int t = __shfl_up(incl, off, 64);
        if (lane >= off) incl += t;
    }
    if (lane == 63) ws[wv] = incl;
    if (threadIdx.x < 64) {
        int b = ((int)threadIdx.x < nb) ? bsum[threadIdx.x] : 0;
        int bi = b;
#pragma unroll
        for (int off = 1; off < 64; off <<= 1) {
            int t = __shfl_up(bi, off, 64);
            if (lane >= off) bi += t;
        }
        int bex = bi - b;
        int mine = __shfl(bex, (int)blockIdx.x, 64);
        if (threadIdx.x == 0) bpre_s = mine;
    }
    __syncthreads();
    if (threadIdx.x == 0) {
        int s = 0;
#pragma unroll
        for (int k = 0; k < 16; ++k) { wo[k] = s; s += ws[k]; }
    }
    __syncthreads();
    if (i < n) start[i] = incl - v + wo[wv] + bpre_s;
}

// ---------------------------------------------------------------------------
// K4: range-split counting-sort CSR fill — zero global atomics.
// ---------------------------------------------------------------------------
__global__ __launch_bounds__(512) void fill3_kernel(const int* __restrict__ src,
                                                    const int* __restrict__ dst,
                                                    const uint* __restrict__ rel,
                                                    const int* __restrict__ start,
                                                    int* __restrict__ csr_src,
                                                    int n_edges, int nwords, int epb, int rwf) {
    __shared__ uint cur[RWF_MAX];
    int c = blockIdx.x >> 3;          // NRF==8
    int r = blockIdx.x & 7;
    int wbeg = r * rwf;
    int wend = min(wbeg + rwf, nwords);
    int nw = wend - wbeg;
    for (int w = threadIdx.x; w < nw; w += 512) cur[w] = 0;
    __syncthreads();
    const uint* relc = rel + (size_t)c * nwords;
    int ebeg = c * epb;
    int eend = min(ebeg + epb, n_edges);
    int nodelo = wbeg * 2, nodehi = wend * 2;
    for (int e = ebeg + (int)threadIdx.x; e < eend; e += 512) {
        int d = dst[e];
        if (d >= nodelo && d < nodehi) {
            int sh = (d & 1) * 16;
            uint old = atomicAdd(&cur[(d >> 1) - wbeg], 1u << sh);
            uint rank = (old >> sh) & 0xffffu;
            uint relv = (relc[d >> 1] >> sh) & 0xffffu;
            int pos = start[d] + (int)(relv + rank);
            csr_src[pos] = src[e];
        }
    }
}

// ---------------------------------------------------------------------------
// K5: FUSED gather+gemm, fine-grained: 32 nodes/block, 256 thr / 4 waves.
// Phase 1: wave handles 2 nodes at a time (half-wave x 32 lanes x uint2),
// unroll-8 => 16 rows in flight/wave. Phase 2: wave = 16-row x 64-col
// quadrant of the 32x128 output tile.
// ---------------------------------------------------------------------------
__global__ __launch_bounds__(256) void gathergemm_kernel(const uint* __restrict__ featn,
                                                         const int* __restrict__ csr_src,
                                                         const int* __restrict__ start,
                                                         const int* __restrict__ deg,
                                                         const ushort* __restrict__ wt_h,
                                                         const float* __restrict__ bias,
                                                         float* __restrict__ out,
                                                         int n_nodes) {
    __shared__ uint rstl[GG_NODES][68];
    int wave = threadIdx.x >> 6;
    int lane = threadIdx.x & 63;
    int base = blockIdx.x * GG_NODES;
    if (base >= n_nodes) return;
    int half = lane >> 5;     // which node of the pair
    int hl   = lane & 31;     // uint2 slot within row

    // ---- phase 1: gather, 2 nodes per wave-pass, 4 passes ----
    for (int p = 0; p < 4; ++p) {
        int node = base + wave * 8 + p * 2 + half;
        int beg = 0, dg = 0;
        if (node < n_nodes) { beg = start[node]; dg = deg[node]; }
        const uint2* fp = (const uint2*)featn;   // row = 32 uint2
        float a0x = 0.f, a0y = 0.f, a1x = 0.f, a1y = 0.f;
        float b0x = 0.f, b0y = 0.f, b1x = 0.f, b1y = 0.f;
        int i = 0;
        for (; i + 7 < dg; i += 8) {
            int s0 = csr_src[beg + i];
            int s1 = csr_src[beg + i + 1];
            int s2 = csr_src[beg + i + 2];
            int s3 = csr_src[beg + i + 3];
            int s4 = csr_src[beg + i + 4];
            int s5 = csr_src[beg + i + 5];
            int s6 = csr_src[beg + i + 6];
            int s7 = csr_src[beg + i + 7];
            uint2 v0 = fp[(size_t)s0 * 32 + hl];
            uint2 v1 = fp[(size_t)s1 * 32 + hl];
            uint2 v2 = fp[(size_t)s2 * 32 + hl];
            uint2 v3 = fp[(size_t)s3 * 32 + hl];
            uint2 v4 = fp[(size_t)s4 * 32 + hl];
            uint2 v5 = fp[(size_t)s5 * 32 + hl];
            uint2 v6 = fp[(size_t)s6 * 32 + hl];
            uint2 v7 = fp[(size_t)s7 * 32 + hl];
            a0x += bflo(v0.x); a0y += bfhi(v0.x); a1x += bflo(v0.y); a1y += bfhi(v0.y);
            b0x += bflo(v1.x); b0y += bfhi(v1.x); b1x += bflo(v1.y); b1y += bfhi(v1.y);
            a0x += bflo(v2.x); a0y += bfhi(v2.x); a1x += bflo(v2.y); a1y += bfhi(v2.y);
            b0x += bflo(v3.x); b0y += bfhi(v3.x); b1x += bflo(v3.y); b1y += bfhi(v3.y);
            a0x += bflo(v4.x); a0y += bfhi(v4.x); a1x += bflo(v4.y); a1y += bfhi(v4.y);
            b0x += bflo(v5.x); b0y += bfhi(v5.x); b1x += bflo(v5.y); b1y += bfhi(v5.y);
            a0x += bflo(v6.x); a0y += bfhi(v6.x); a1x += bflo(v6.y); a1y += bfhi(v6.y);
            b0x += bflo(v7.x); b0y += bfhi(v7.x); b1x += bflo(v7.y); b1y += bfhi(v7.y);
        }
        for (; i + 1 < dg; i += 2) {
            int s0 = csr_src[beg + i];
            int s1 = csr_src[beg + i + 1];
            uint2 v0 = fp[(size_t)s0 * 32 + hl];
            uint2 v1 = fp[(size_t)s1 * 32 + hl];
            a0x += bflo(v0.x); a0y += bfhi(v0.x); a1x += bflo(v0.y); a1y += bfhi(v0.y);
            b0x += bflo(v1.x); b0y += bfhi(v1.x); b1x += bflo(v1.y); b1y += bfhi(v1.y);
        }
        if (i < dg) {
            int s = csr_src[beg + i];
            uint2 v = fp[(size_t)s * 32 + hl];
            a0x += bflo(v.x); a0y += bfhi(v.x); a1x += bflo(v.y); a1y += bfhi(v.y);
        }
        float r0x = a0x + b0x, r0y = a0y + b0y;
        float r1x = a1x + b1x, r1y = a1y + b1y;
        uint w0 = (uint)f2bf(r0x) | ((uint)f2bf(r0y) << 16);
        uint w1 = (uint)f2bf(r1x) | ((uint)f2bf(r1y) << 16);
        *(uint2*)&rstl[wave * 8 + p * 2 + half][hl * 2] = make_uint2(w0, w1);
    }
    __syncthreads();

    // ---- phase 2: MFMA. wave -> rows (wave&1)*16, col tiles (wave>>1)*4 ----
    int l16 = lane & 15, lq = lane >> 4;
    int r0 = (wave & 1) * 16;
    int nt0 = (wave >> 1) * 4;

    short8 a[4];
#pragma unroll
    for (int kt = 0; kt < 4; ++kt)
        a[kt] = *(const short8*)&rstl[r0 + l16][kt * 16 + lq * 4];

#pragma unroll
    for (int t = 0; t < 4; ++t) {
        int nt = nt0 + t;
        f32x4 acc = {0.0f, 0.0f, 0.0f, 0.0f};
        const ushort* bp = wt_h + (size_t)(nt * 16 + l16) * NF + lq * 8;
#pragma unroll
        for (int kt = 0; kt < 4; ++kt) {
            short8 b = *(const short8*)(bp + kt * 32);
            acc = __builtin_amdgcn_mfma_f32_16x16x32_bf16(a[kt], b, acc, 0, 0, 0);
        }
        int col = nt * 16 + l16;
        float bv = bias[col];
#pragma unroll
        for (int r = 0; r < 4; ++r) {
            int orow = base + r0 + lq * 4 + r;
            if (orow < n_nodes) {
                float v = acc[r] + bv;
                out[(size_t)orow * NF + col] = v > 0.0f ? v : 0.0f;
            }
        }
    }
}

// ======================= fallback path (robustness) =========================
__global__ __launch_bounds__(256) void deg_kernel(const int* __restrict__ src,
                                                  const int* __restrict__ dst,
                                                  int* __restrict__ deg_out,
                                                  int* __restrict__ deg_in,
                                                  int n_edges) {
    int i = blockIdx.x * 256 + threadIdx.x;
    if (i < n_edges) {
        atomicAdd(&deg_out[src[i]], 1);
        atomicAdd(&deg_in[dst[i]], 1);
    }
}
__global__ __launch_bounds__(256) void norm_kernel(const int* __restrict__ deg_out,
                                                   const int* __restrict__ deg_in,
                                                   float* __restrict__ norm, int n) {
    int i = blockIdx.x * 256 + threadIdx.x;
    if (i < n) {
        int dov = deg_out[i]; if (dov < 1) dov = 1;
        int div_ = deg_in[i]; if (div_ < 1) div_ = 1;
        norm[i] = 1.0f / sqrtf((float)dov * (float)div_);
    }
}
__global__ __launch_bounds__(256) void prep_kernel(const float* __restrict__ feat,
                                                   const float* __restrict__ norm,
                                                   uint* __restrict__ featn, int total,
                                                   const float* __restrict__ W,
                                                   uint* __restrict__ wt, int nfb) {
    if ((int)blockIdx.x < nfb) {
        int idx = blockIdx.x * 256 + threadIdx.x;
        if (idx >= total) return;
        int node = idx >> 6;
        float nv = norm[node];
        float2 v = ((const float2*)feat)[idx];
        featn[idx] = (uint)f2bf(v.x * nv) | ((uint)f2bf(v.y * nv) << 16);
    } else {
        int idx = (blockIdx.x - nfb) * 256 + threadIdx.x;
        if (idx >= NF * NF / 2) return;
        int nrow = idx >> 6;
        int k2 = idx & 63;
        float a = W[(2 * k2) * NF + nrow];
        float b = W[(2 * k2 + 1) * NF + nrow];
        wt[idx] = (uint)f2bf(a) | ((uint)f2bf(b) << 16);
    }
}
__global__ __launch_bounds__(1024) void scan_sum_kernel(const int* __restrict__ deg,
                                                        int* __restrict__ bsum, int n) {
    int i = blockIdx.x * 1024 + threadIdx.x;
    int v = (i < n) ? deg[i] : 0;
#pragma unroll
    for (int off = 32; off >= 1; off >>= 1) v += __shfl_down(v, off, 64);
    __shared__ int ws[16];
    int wv = threadIdx.x >> 6, lane = threadIdx.x & 63;
    if (lane == 0) ws[wv] = v;
    __syncthreads();
    if (threadIdx.x == 0) {
        int s = 0;
#pragma unroll
        for (int k = 0; k < 16; ++k) s += ws[k];
        bsum[blockIdx.x] = s;
    }
}
__global__ __launch_bounds__(1024) void scan_bsum_kernel(int* __restrict__ bsum, int nb) {
    __shared__ int s[1024];
    int v = (threadIdx.x < (unsigned)nb) ? bsum[threadIdx.x] : 0;
    s[threadIdx.x] = v;
    __syncthreads();
    for (int off = 1; off < 1024; off <<= 1) {
        int t = (threadIdx.x >= (unsigned)off) ? s[threadIdx.x - off] : 0;
        __syncthreads();
        s[threadIdx.x] += t;
        __syncthreads();
    }
    if (threadIdx.x < (unsigned)nb) bsum[threadIdx.x] = s[threadIdx.x] - v;
}
__global__ __launch_bounds__(1024) void scan_final_kernel(const int* __restrict__ deg,
                                                          const int* __restrict__ bsum,
                                                          int* __restrict__ start,
                                                          int* __restrict__ cursor, int n) {
    int i = blockIdx.x * 1024 + threadIdx.x;
    int v = (i < n) ? deg[i] : 0;
    int lane = threadIdx.x & 63, wv = threadIdx.x >> 6;
    int incl = v;
#pragma unroll
    for (int off = 1; off < 64; off <<= 1) {
        int t = __shfl_up(incl, off, 64);
        if (lane >= off) incl += t;
    }
    __shared__ int ws[16];
    __shared__ int wo[16];
    if (lane == 63) ws[wv] = incl;
    __syncthreads();
    if (threadIdx.x == 0) {
        int s = 0;
#pragma unroll
        for (int k = 0; k < 16; ++k) { wo[k] = s; s += ws[k]; }
    }
    __syncthreads();
    int excl = incl - v + wo[wv] + bsum[blockIdx.x];
    if (i < n) { start[i] = excl; cursor[i] = excl; }
}
__global__ __launch_bounds__(256) void fill_kernel(const int* __restrict__ src,
                                                   const int* __restrict__ dst,
                                                   int* __restrict__ cursor,
                                                   int* __restrict__ csr_src,
                                                   int n_edges) {
    int e = blockIdx.x * 256 + threadIdx.x;
    if (e < n_edges) {
        int d = dst[e];
        int pos = atomicAdd(&cursor[d], 1);
        csr_src[pos] = src[e];
    }
}
__global__ __launch_bounds__(256) void gather_kernel(const uint* __restrict__ featn,
                                                     const int* __restrict__ csr_src,
                                                     const int* __restrict__ start,
                                                     const int* __restrict__ deg,
                                                     uint* __restrict__ rst_h,
                                                     int n_nodes) {
    int wid  = (blockIdx.x * 256 + threadIdx.x) >> 6;
    int lane = threadIdx.x & 63;
    if (wid >= n_nodes) return;
    int beg = start[wid];
    int end = beg + deg[wid];
    float ax = 0.f, ay = 0.f;
    for (int i = beg; i < end; ++i) {
        int s = csr_src[i];
        uint v = featn[(size_t)s * 64 + lane];
        ax += bflo(v); ay += bfhi(v);
    }
    rst_h[(size_t)wid * 64 + lane] = (uint)f2bf(ax) | ((uint)f2bf(ay) << 16);
}
__global__ __launch_bounds__(256) void gemm_mfma_kernel(const ushort* __restrict__ rst_h,
                                                        const ushort* __restrict__ wt_h,
                                                        const float* __restrict__ bias,
                                                        float* __restrict__ out,
                                                        int n_nodes) {
    int wave = threadIdx.x >> 6;
    int lane = threadIdx.x & 63;
    int row0 = blockIdx.x * 64 + wave * 16;
    if (row0 >= n_nodes) return;
    int l16 = lane & 15, lq = lane >> 4;
    short8 a[4];
    const ushort* ap = rst_h + (size_t)(row0 + l16) * NF + lq * 8;
#pragma unroll
    for (int kt = 0; kt < 4; ++kt) a[kt] = *(const short8*)(ap + kt * 32);
#pragma unroll
    for (int nt = 0; nt < 8; ++nt) {
        f32x4 acc = {0.0f, 0.0f, 0.0f, 0.0f};
        const ushort* bp = wt_h + (size_t)(nt * 16 + l16) * NF + lq * 8;
#pragma unroll
        for (int kt = 0; kt < 4; ++kt) {
            short8 b = *(const short8*)(bp + kt * 32);
            acc = __builtin_amdgcn_mfma_f32_16x16x32_bf16(a[kt], b, acc, 0, 0, 0);
        }
        int col = nt * 16 + l16;
        float bv = bias[col];
#pragma unroll
        for (int r = 0; r < 4; ++r) {
            int orow = row0 + lq * 4 + r;
            if (orow < n_nodes) {
                float v = acc[r] + bv;
                out[(size_t)orow * NF + col] = v > 0.0f ? v : 0.0f;
            }
        }
    }
}
// ===========================================================================

extern "C" void kernel_launch(void* const* d_in, const int* in_sizes, int n_in,
                              void* d_out, int out_size, void* d_ws, size_t ws_size,
                              hipStream_t stream) {
    const float* feat = (const float*)d_in[0];
    const float* W    = (const float*)d_in[1];
    const float* bias = (const float*)d_in[2];
    const int*   src  = (const int*)d_in[3];
    const int*   dst  = (const int*)d_in[4];

    int n_nodes = in_sizes[0] / NF;
    int n_edges = in_sizes[3];

    char* ws = (char*)d_ws;
    size_t row_u32 = (size_t)n_nodes * 64;
    uint*  rst_h   = (uint*)ws;
    uint*  featn   = rst_h + row_u32;
    int*   deg_in  = (int*)(featn + row_u32);
    int*   deg_out = deg_in + n_nodes;
    float* norm    = (float*)(deg_out + n_nodes);
    int*   start   = (int*)(norm + n_nodes);
    int*   cursor  = start + n_nodes;
    int*   bsum    = cursor + n_nodes;
    uint*  wt      = (uint*)(bsum + 1024);
    int*   csr_src = (int*)(wt + NF * NF / 2);
    uint*  partial_in = (uint*)(csr_src + n_edges);

    int nwords = (n_nodes + 1) / 2;
    uint* partial_out = partial_in + (size_t)NCHUNK * nwords;
    size_t need = (size_t)((char*)(partial_out + (size_t)NCHUNK * nwords) - ws);

    int epb = (n_edges + NCHUNK - 1) / NCHUNK;
    int nb1024 = (n_nodes + 1023) / 1024;
    bool fast = (nwords <= NNW_MAX) && (epb < 65536) && (nb1024 <= 64) && (need <= ws_size);

    int total = n_nodes * 64;
    int nfb = (total + 255) / 256;

    if (fast) {
        int rwh = (nwords + NRH - 1) / NRH;
        hist_kernel<<<dim3(NCHUNK, 2, NRH), 512, 0, stream>>>(
            src, dst, partial_in, partial_out, n_edges, nwords, epb, rwh);
        dnrp_kernel<<<nb1024, 512, 0, stream>>>(partial_in, partial_out, deg_in, norm,
                                                bsum, feat, featn, nwords, n_nodes, total);
        scan2wt_kernel<<<nb1024 + 8, 1024, 0, stream>>>(deg_in, bsum, start,
                                                        n_nodes, nb1024, W, wt);
        int rwf = (nwords + NRF - 1) / NRF;
        fill3_kernel<<<NCHUNK * NRF, 512, 0, stream>>>(src, dst, partial_out, start,
                                                       csr_src, n_edges, nwords, epb, rwf);
        gathergemm_kernel<<<(n_nodes + GG_NODES - 1) / GG_NODES, 256, 0, stream>>>(
            featn, csr_src, start, deg_in, (const ushort*)wt, bias, (float*)d_out, n_nodes);
    } else {
        hipMemsetAsync(deg_in, 0, 2 * (size_t)n_nodes * sizeof(int), stream);
        deg_kernel<<<(n_edges + 255) / 256, 256, 0, stream>>>(src, dst, deg_out, deg_in, n_edges);
        norm_kernel<<<(n_nodes + 255) / 256, 256, 0, stream>>>(deg_out, deg_in, norm, n_nodes);
        prep_kernel<<<nfb + 32, 256, 0, stream>>>(feat, norm, featn, total, W, wt, nfb);
        int nb = (n_nodes + 1023) / 1024;
        scan_sum_kernel<<<nb, 1024, 0, stream>>>(deg_in, bsum, n_nodes);
        scan_bsum_kernel<<<1, 1024, 0, stream>>>(bsum, nb);
        scan_final_kernel<<<nb, 1024, 0, stream>>>(deg_in, bsum, start, cursor, n_nodes);
        fill_kernel<<<(n_edges + 255) / 256, 256, 0, stream>>>(src, dst, cursor, csr_src, n_edges);
        gather_kernel<<<(n_nodes * 64 + 255) / 256, 256, 0, stream>>>(featn, csr_src, start,
                                                                      deg_in, rst_h, n_nodes);
        gemm_mfma_kernel<<<(n_nodes + 63) / 64, 256, 0, stream>>>((const ushort*)rst_h,
                                                                  (const ushort*)wt, bias,
                                                                  (float*)d_out, n_nodes);
    }
}

// Round 13
// 118.692 us; speedup vs baseline: 1.2896x; 1.2896x over previous
//
#include <hip/hip_runtime.h>

#define NF 128
#define NCHUNK 32          // edge chunks
#define NRH 4              // hist node-range splits (LDS 25KB)
#define NRF 8              // fill node-range splits (LDS 12.5KB)
#define NNW_MAX 25088      // max packed u16-pair words; n_nodes <= 50176
#define RWH_MAX ((NNW_MAX + NRH - 1) / NRH)
#define RWF_MAX ((NNW_MAX + NRF - 1) / NRF)
#define GG_NODES 32        // nodes per fused gather+gemm block (fine-grained)

typedef __attribute__((ext_vector_type(8))) short short8;   // 8 x bf16
typedef __attribute__((ext_vector_type(4))) float f32x4;
typedef unsigned int uint;
typedef unsigned short ushort;

__device__ __forceinline__ ushort f2bf(float f) {
    uint u = __float_as_uint(f);
    uint r = (u + 0x7fffu + ((u >> 16) & 1u)) >> 16;
    return (ushort)r;
}
__device__ __forceinline__ float bflo(uint v) { return __uint_as_float(v << 16); }
__device__ __forceinline__ float bfhi(uint v) { return __uint_as_float(v & 0xffff0000u); }

// ---------------------------------------------------------------------------
// K1: range-split LDS degree histograms (no global atomics).
// ---------------------------------------------------------------------------
__global__ __launch_bounds__(512) void hist_kernel(const int* __restrict__ src,
                                                   const int* __restrict__ dst,
                                                   uint* __restrict__ partial_in,
                                                   uint* __restrict__ partial_out,
                                                   int n_edges, int nwords, int epb, int rw) {
    __shared__ uint h[RWH_MAX];
    int wbeg = blockIdx.z * rw;
    int wend = min(wbeg + rw, nwords);
    int nw = wend - wbeg;
    for (int w = threadIdx.x; w < nw; w += 512) h[w] = 0;
    __syncthreads();
    const int* idx = blockIdx.y ? src : dst;
    int ebeg = blockIdx.x * epb;
    int eend = min(ebeg + epb, n_edges);
    int nodelo = wbeg * 2, nodehi = wend * 2;
    for (int e = ebeg + (int)threadIdx.x; e < eend; e += 512) {
        int node = idx[e];
        if (node >= nodelo && node < nodehi)
            atomicAdd(&h[(node >> 1) - wbeg], 1u << ((node & 1) * 16));
    }
    __syncthreads();
    uint* p = (blockIdx.y ? partial_out : partial_in) + (size_t)blockIdx.x * nwords + wbeg;
    for (int w = threadIdx.x; w < nw; w += 512) p[w] = h[w];
}

// ---------------------------------------------------------------------------
// K2: partials -> deg_in[], norm[], rel[c][w] in-place, bsum[b]. (R11 form —
// the R12 fusion with feature conversion serialized 25.6MB onto 49 blocks,
// occupancy 3.8%; feature conversion must stay full-grid.)
// ---------------------------------------------------------------------------
__global__ __launch_bounds__(512) void dnr_kernel(const uint* __restrict__ partial_in,
                                                  uint* __restrict__ partial_out,
                                                  int* __restrict__ deg_in,
                                                  float* __restrict__ norm,
                                                  int* __restrict__ bsum,
                                                  int nwords, int n) {
    int w = blockIdx.x * 512 + (int)threadIdx.x;
    uint si0 = 0, si1 = 0, so0 = 0, so1 = 0;
    if (w < nwords) {
        for (int c = 0; c < NCHUNK; ++c) {
            uint vi = partial_in[(size_t)c * nwords + w];
            uint vo = partial_out[(size_t)c * nwords + w];
            partial_out[(size_t)c * nwords + w] = si0 | (si1 << 16);   // rel
            si0 += vi & 0xffffu; si1 += vi >> 16;
            so0 += vo & 0xffffu; so1 += vo >> 16;
        }
        int n0 = 2 * w, n1 = 2 * w + 1;
        {
            uint di = si0 < 1u ? 1u : si0, dv = so0 < 1u ? 1u : so0;
            deg_in[n0] = (int)si0;
            norm[n0] = 1.0f / sqrtf((float)di * (float)dv);
        }
        if (n1 < n) {
            uint di = si1 < 1u ? 1u : si1, dv = so1 < 1u ? 1u : so1;
            deg_in[n1] = (int)si1;
            norm[n1] = 1.0f / sqrtf((float)di * (float)dv);
        }
    }
    int v = (int)(si0 + si1);
#pragma unroll
    for (int off = 32; off >= 1; off >>= 1) v += __shfl_down(v, off, 64);
    __shared__ int wsum[8];
    int wave = threadIdx.x >> 6, lane = threadIdx.x & 63;
    if (lane == 0) wsum[wave] = v;
    __syncthreads();
    if (threadIdx.x == 0) {
        int s = 0;
#pragma unroll
        for (int k = 0; k < 8; ++k) s += wsum[k];
        bsum[blockIdx.x] = s;
    }
}

// ---------------------------------------------------------------------------
// K3: prep = featn (bf16(feat*norm)) UNION wt (W^T bf16) — full grid.
// ---------------------------------------------------------------------------
__global__ __launch_bounds__(256) void prep_kernel(const float* __restrict__ feat,
                                                   const float* __restrict__ norm,
                                                   uint* __restrict__ featn, int total,
                                                   const float* __restrict__ W,
                                                   uint* __restrict__ wt, int nfb) {
    if ((int)blockIdx.x < nfb) {
        int idx = blockIdx.x * 256 + threadIdx.x;
        if (idx >= total) return;
        int node = idx >> 6;
        float nv = norm[node];
        float2 v = ((const float2*)feat)[idx];
        featn[idx] = (uint)f2bf(v.x * nv) | ((uint)f2bf(v.y * nv) << 16);
    } else {
        int idx = (blockIdx.x - nfb) * 256 + threadIdx.x;
        if (idx >= NF * NF / 2) return;
        int nrow = idx >> 6;
        int k2 = idx & 63;
        float a = W[(2 * k2) * NF + nrow];
        float b = W[(2 * k2 + 1) * NF + nrow];
        wt[idx] = (uint)f2bf(a) | ((uint)f2bf(b) << 16);
    }
}

// ---------------------------------------------------------------------------
// K4: scan_final2 — block scan + in-wave prescan of bsum (nb <= 64)
// ---------------------------------------------------------------------------
__global__ __launch_bounds__(1024) void scan_final2_kernel(const int* __restrict__ deg,
                                                           const int* __restrict__ bsum,
                                                           int* __restrict__ start,
                                                           int n, int nb) {
    __shared__ int ws[16];
    __shared__ int wo[16];
    __shared__ int bpre_s;
    int i = blockIdx.x * 1024 + (int)threadIdx.x;
    int v = (i < n) ? deg[i] : 0;
    int lane = threadIdx.x & 63, wv = threadIdx.x >> 6;
    int incl = v;
#pragma unroll
    for (int off = 1; off < 64; off <<= 1) {
        int t = __shfl_up(incl, off, 64);
        if (lane >= off) incl += t;
    }
    if (lane == 63) ws[wv] = incl;
    if (threadIdx.x < 64) {
        int b = ((int)threadIdx.x < nb) ? bsum[threadIdx.x] : 0;
        int bi = b;
#pragma unroll
        for (int off = 1; off < 64; off <<= 1) {
            int t = __shfl_up(bi, off, 64);
            if (lane >= off) bi += t;
        }
        int bex = bi - b;
        int mine = __shfl(bex, (int)blockIdx.x, 64);
        if (threadIdx.x == 0) bpre_s = mine;
    }
    __syncthreads();
    if (threadIdx.x == 0) {
        int s = 0;
#pragma unroll
        for (int k = 0; k < 16; ++k) { wo[k] = s; s += ws[k]; }
    }
    __syncthreads();
    if (i < n) start[i] = incl - v + wo[wv] + bpre_s;
}

// ---------------------------------------------------------------------------
// K5: range-split counting-sort CSR fill — zero global atomics.
// ---------------------------------------------------------------------------
__global__ __launch_bounds__(512) void fill3_kernel(const int* __restrict__ src,
                                                    const int* __restrict__ dst,
                                                    const uint* __restrict__ rel,
                                                    const int* __restrict__ start,
                                                    int* __restrict__ csr_src,
                                                    int n_edges, int nwords, int epb, int rwf) {
    __shared__ uint cur[RWF_MAX];
    int c = blockIdx.x >> 3;          // NRF==8
    int r = blockIdx.x & 7;
    int wbeg = r * rwf;
    int wend = min(wbeg + rwf, nwords);
    int nw = wend - wbeg;
    for (int w = threadIdx.x; w < nw; w += 512) cur[w] = 0;
    __syncthreads();
    const uint* relc = rel + (size_t)c * nwords;
    int ebeg = c * epb;
    int eend = min(ebeg + epb, n_edges);
    int nodelo = wbeg * 2, nodehi = wend * 2;
    for (int e = ebeg + (int)threadIdx.x; e < eend; e += 512) {
        int d = dst[e];
        if (d >= nodelo && d < nodehi) {
            int sh = (d & 1) * 16;
            uint old = atomicAdd(&cur[(d >> 1) - wbeg], 1u << sh);
            uint rank = (old >> sh) & 0xffffu;
            uint relv = (relc[d >> 1] >> sh) & 0xffffu;
            int pos = start[d] + (int)(relv + rank);
            csr_src[pos] = src[e];
        }
    }
}

// ---------------------------------------------------------------------------
// K6: FUSED gather+gemm, fine-grained: 32 nodes/block, 256 thr / 4 waves.
// Phase 1: wave handles 2 nodes at a time (half-wave x 32 lanes x uint2),
// unroll-8 => 16 rows in flight/wave. Phase 2: wave = 16-row x 64-col
// quadrant of the 32x128 output tile.
// ---------------------------------------------------------------------------
__global__ __launch_bounds__(256) void gathergemm_kernel(const uint* __restrict__ featn,
                                                         const int* __restrict__ csr_src,
                                                         const int* __restrict__ start,
                                                         const int* __restrict__ deg,
                                                         const ushort* __restrict__ wt_h,
                                                         const float* __restrict__ bias,
                                                         float* __restrict__ out,
                                                         int n_nodes) {
    __shared__ uint rstl[GG_NODES][68];
    int wave = threadIdx.x >> 6;
    int lane = threadIdx.x & 63;
    int base = blockIdx.x * GG_NODES;
    if (base >= n_nodes) return;
    int half = lane >> 5;     // which node of the pair
    int hl   = lane & 31;     // uint2 slot within row

    // ---- phase 1: gather, 2 nodes per wave-pass, 4 passes ----
    for (int p = 0; p < 4; ++p) {
        int node = base + wave * 8 + p * 2 + half;
        int beg = 0, dg = 0;
        if (node < n_nodes) { beg = start[node]; dg = deg[node]; }
        const uint2* fp = (const uint2*)featn;   // row = 32 uint2
        float a0x = 0.f, a0y = 0.f, a1x = 0.f, a1y = 0.f;
        float b0x = 0.f, b0y = 0.f, b1x = 0.f, b1y = 0.f;
        int i = 0;
        for (; i + 7 < dg; i += 8) {
            int s0 = csr_src[beg + i];
            int s1 = csr_src[beg + i + 1];
            int s2 = csr_src[beg + i + 2];
            int s3 = csr_src[beg + i + 3];
            int s4 = csr_src[beg + i + 4];
            int s5 = csr_src[beg + i + 5];
            int s6 = csr_src[beg + i + 6];
            int s7 = csr_src[beg + i + 7];
            uint2 v0 = fp[(size_t)s0 * 32 + hl];
            uint2 v1 = fp[(size_t)s1 * 32 + hl];
            uint2 v2 = fp[(size_t)s2 * 32 + hl];
            uint2 v3 = fp[(size_t)s3 * 32 + hl];
            uint2 v4 = fp[(size_t)s4 * 32 + hl];
            uint2 v5 = fp[(size_t)s5 * 32 + hl];
            uint2 v6 = fp[(size_t)s6 * 32 + hl];
            uint2 v7 = fp[(size_t)s7 * 32 + hl];
            a0x += bflo(v0.x); a0y += bfhi(v0.x); a1x += bflo(v0.y); a1y += bfhi(v0.y);
            b0x += bflo(v1.x); b0y += bfhi(v1.x); b1x += bflo(v1.y); b1y += bfhi(v1.y);
            a0x += bflo(v2.x); a0y += bfhi(v2.x); a1x += bflo(v2.y); a1y += bfhi(v2.y);
            b0x += bflo(v3.x); b0y += bfhi(v3.x); b1x += bflo(v3.y); b1y += bfhi(v3.y);
            a0x += bflo(v4.x); a0y += bfhi(v4.x); a1x += bflo(v4.y); a1y += bfhi(v4.y);
            b0x += bflo(v5.x); b0y += bfhi(v5.x); b1x += bflo(v5.y); b1y += bfhi(v5.y);
            a0x += bflo(v6.x); a0y += bfhi(v6.x); a1x += bflo(v6.y); a1y += bfhi(v6.y);
            b0x += bflo(v7.x); b0y += bfhi(v7.x); b1x += bflo(v7.y); b1y += bfhi(v7.y);
        }
        for (; i + 1 < dg; i += 2) {
            int s0 = csr_src[beg + i];
            int s1 = csr_src[beg + i + 1];
            uint2 v0 = fp[(size_t)s0 * 32 + hl];
            uint2 v1 = fp[(size_t)s1 * 32 + hl];
            a0x += bflo(v0.x); a0y += bfhi(v0.x); a1x += bflo(v0.y); a1y += bfhi(v0.y);
            b0x += bflo(v1.x); b0y += bfhi(v1.x); b1x += bflo(v1.y); b1y += bfhi(v1.y);
        }
        if (i < dg) {
            int s = csr_src[beg + i];
            uint2 v = fp[(size_t)s * 32 + hl];
            a0x += bflo(v.x); a0y += bfhi(v.x); a1x += bflo(v.y); a1y += bfhi(v.y);
        }
        float r0x = a0x + b0x, r0y = a0y + b0y;
        float r1x = a1x + b1x, r1y = a1y + b1y;
        uint w0 = (uint)f2bf(r0x) | ((uint)f2bf(r0y) << 16);
        uint w1 = (uint)f2bf(r1x) | ((uint)f2bf(r1y) << 16);
        *(uint2*)&rstl[wave * 8 + p * 2 + half][hl * 2] = make_uint2(w0, w1);
    }
    __syncthreads();

    // ---- phase 2: MFMA. wave -> rows (wave&1)*16, col tiles (wave>>1)*4 ----
    int l16 = lane & 15, lq = lane >> 4;
    int r0 = (wave & 1) * 16;
    int nt0 = (wave >> 1) * 4;

    short8 a[4];
#pragma unroll
    for (int kt = 0; kt < 4; ++kt)
        a[kt] = *(const short8*)&rstl[r0 + l16][kt * 16 + lq * 4];

#pragma unroll
    for (int t = 0; t < 4; ++t) {
        int nt = nt0 + t;
        f32x4 acc = {0.0f, 0.0f, 0.0f, 0.0f};
        const ushort* bp = wt_h + (size_t)(nt * 16 + l16) * NF + lq * 8;
#pragma unroll
        for (int kt = 0; kt < 4; ++kt) {
            short8 b = *(const short8*)(bp + kt * 32);
            acc = __builtin_amdgcn_mfma_f32_16x16x32_bf16(a[kt], b, acc, 0, 0, 0);
        }
        int col = nt * 16 + l16;
        float bv = bias[col];
#pragma unroll
        for (int r = 0; r < 4; ++r) {
            int orow = base + r0 + lq * 4 + r;
            if (orow < n_nodes) {
                float v = acc[r] + bv;
                out[(size_t)orow * NF + col] = v > 0.0f ? v : 0.0f;
            }
        }
    }
}

// ======================= fallback path (robustness) =========================
__global__ __launch_bounds__(256) void deg_kernel(const int* __restrict__ src,
                                                  const int* __restrict__ dst,
                                                  int* __restrict__ deg_out,
                                                  int* __restrict__ deg_in,
                                                  int n_edges) {
    int i = blockIdx.x * 256 + threadIdx.x;
    if (i < n_edges) {
        atomicAdd(&deg_out[src[i]], 1);
        atomicAdd(&deg_in[dst[i]], 1);
    }
}
__global__ __launch_bounds__(256) void norm_kernel(const int* __restrict__ deg_out,
                                                   const int* __restrict__ deg_in,
                                                   float* __restrict__ norm, int n) {
    int i = blockIdx.x * 256 + threadIdx.x;
    if (i < n) {
        int dov = deg_out[i]; if (dov < 1) dov = 1;
        int div_ = deg_in[i]; if (div_ < 1) div_ = 1;
        norm[i] = 1.0f / sqrtf((float)dov * (float)div_);
    }
}
__global__ __launch_bounds__(1024) void scan_sum_kernel(const int* __restrict__ deg,
                                                        int* __restrict__ bsum, int n) {
    int i = blockIdx.x * 1024 + threadIdx.x;
    int v = (i < n) ? deg[i] : 0;
#pragma unroll
    for (int off = 32; off >= 1; off >>= 1) v += __shfl_down(v, off, 64);
    __shared__ int ws[16];
    int wv = threadIdx.x >> 6, lane = threadIdx.x & 63;
    if (lane == 0) ws[wv] = v;
    __syncthreads();
    if (threadIdx.x == 0) {
        int s = 0;
#pragma unroll
        for (int k = 0; k < 16; ++k) s += ws[k];
        bsum[blockIdx.x] = s;
    }
}
__global__ __launch_bounds__(1024) void scan_bsum_kernel(int* __restrict__ bsum, int nb) {
    __shared__ int s[1024];
    int v = (threadIdx.x < (unsigned)nb) ? bsum[threadIdx.x] : 0;
    s[threadIdx.x] = v;
    __syncthreads();
    for (int off = 1; off < 1024; off <<= 1) {
        int t = (threadIdx.x >= (unsigned)off) ? s[threadIdx.x - off] : 0;
        __syncthreads();
        s[threadIdx.x] += t;
        __syncthreads();
    }
    if (threadIdx.x < (unsigned)nb) bsum[threadIdx.x] = s[threadIdx.x] - v;
}
__global__ __launch_bounds__(1024) void scan_final_kernel(const int* __restrict__ deg,
                                                          const int* __restrict__ bsum,
                                                          int* __restrict__ start,
                                                          int* __restrict__ cursor, int n) {
    int i = blockIdx.x * 1024 + threadIdx.x;
    int v = (i < n) ? deg[i] : 0;
    int lane = threadIdx.x & 63, wv = threadIdx.x >> 6;
    int incl = v;
#pragma unroll
    for (int off = 1; off < 64; off <<= 1) {
        int t = __shfl_up(incl, off, 64);
        if (lane >= off) incl += t;
    }
    __shared__ int ws[16];
    __shared__ int wo[16];
    if (lane == 63) ws[wv] = incl;
    __syncthreads();
    if (threadIdx.x == 0) {
        int s = 0;
#pragma unroll
        for (int k = 0; k < 16; ++k) { wo[k] = s; s += ws[k]; }
    }
    __syncthreads();
    int excl = incl - v + wo[wv] + bsum[blockIdx.x];
    if (i < n) { start[i] = excl; cursor[i] = excl; }
}
__global__ __launch_bounds__(256) void fill_kernel(const int* __restrict__ src,
                                                   const int* __restrict__ dst,
                                                   int* __restrict__ cursor,
                                                   int* __restrict__ csr_src,
                                                   int n_edges) {
    int e = blockIdx.x * 256 + threadIdx.x;
    if (e < n_edges) {
        int d = dst[e];
        int pos = atomicAdd(&cursor[d], 1);
        csr_src[pos] = src[e];
    }
}
__global__ __launch_bounds__(256) void gather_kernel(const uint* __restrict__ featn,
                                                     const int* __restrict__ csr_src,
                                                     const int* __restrict__ start,
                                                     const int* __restrict__ deg,
                                                     uint* __restrict__ rst_h,
                                                     int n_nodes) {
    int wid  = (blockIdx.x * 256 + threadIdx.x) >> 6;
    int lane = threadIdx.x & 63;
    if (wid >= n_nodes) return;
    int beg = start[wid];
    int end = beg + deg[wid];
    float ax = 0.f, ay = 0.f;
    for (int i = beg; i < end; ++i) {
        int s = csr_src[i];
        uint v = featn[(size_t)s * 64 + lane];
        ax += bflo(v); ay += bfhi(v);
    }
    rst_h[(size_t)wid * 64 + lane] = (uint)f2bf(ax) | ((uint)f2bf(ay) << 16);
}
__global__ __launch_bounds__(256) void gemm_mfma_kernel(const ushort* __restrict__ rst_h,
                                                        const ushort* __restrict__ wt_h,
                                                        const float* __restrict__ bias,
                                                        float* __restrict__ out,
                                                        int n_nodes) {
    int wave = threadIdx.x >> 6;
    int lane = threadIdx.x & 63;
    int row0 = blockIdx.x * 64 + wave * 16;
    if (row0 >= n_nodes) return;
    int l16 = lane & 15, lq = lane >> 4;
    short8 a[4];
    const ushort* ap = rst_h + (size_t)(row0 + l16) * NF + lq * 8;
#pragma unroll
    for (int kt = 0; kt < 4; ++kt) a[kt] = *(const short8*)(ap + kt * 32);
#pragma unroll
    for (int nt = 0; nt < 8; ++nt) {
        f32x4 acc = {0.0f, 0.0f, 0.0f, 0.0f};
        const ushort* bp = wt_h + (size_t)(nt * 16 + l16) * NF + lq * 8;
#pragma unroll
        for (int kt = 0; kt < 4; ++kt) {
            short8 b = *(const short8*)(bp + kt * 32);
            acc = __builtin_amdgcn_mfma_f32_16x16x32_bf16(a[kt], b, acc, 0, 0, 0);
        }
        int col = nt * 16 + l16;
        float bv = bias[col];
#pragma unroll
        for (int r = 0; r < 4; ++r) {
            int orow = row0 + lq * 4 + r;
            if (orow < n_nodes) {
                float v = acc[r] + bv;
                out[(size_t)orow * NF + col] = v > 0.0f ? v : 0.0f;
            }
        }
    }
}
// ===========================================================================

extern "C" void kernel_launch(void* const* d_in, const int* in_sizes, int n_in,
                              void* d_out, int out_size, void* d_ws, size_t ws_size,
                              hipStream_t stream) {
    const float* feat = (const float*)d_in[0];
    const float* W    = (const float*)d_in[1];
    const float* bias = (const float*)d_in[2];
    const int*   src  = (const int*)d_in[3];
    const int*   dst  = (const int*)d_in[4];

    int n_nodes = in_sizes[0] / NF;
    int n_edges = in_sizes[3];

    char* ws = (char*)d_ws;
    size_t row_u32 = (size_t)n_nodes * 64;
    uint*  rst_h   = (uint*)ws;
    uint*  featn   = rst_h + row_u32;
    int*   deg_in  = (int*)(featn + row_u32);
    int*   deg_out = deg_in + n_nodes;
    float* norm    = (float*)(deg_out + n_nodes);
    int*   start   = (int*)(norm + n_nodes);
    int*   cursor  = start + n_nodes;
    int*   bsum    = cursor + n_nodes;
    uint*  wt      = (uint*)(bsum + 1024);
    int*   csr_src = (int*)(wt + NF * NF / 2);
    uint*  partial_in = (uint*)(csr_src + n_edges);

    int nwords = (n_nodes + 1) / 2;
    uint* partial_out = partial_in + (size_t)NCHUNK * nwords;
    size_t need = (size_t)((char*)(partial_out + (size_t)NCHUNK * nwords) - ws);

    int epb = (n_edges + NCHUNK - 1) / NCHUNK;
    int nb1024 = (n_nodes + 1023) / 1024;
    bool fast = (nwords <= NNW_MAX) && (epb < 65536) && (nb1024 <= 64) && (need <= ws_size);

    int total = n_nodes * 64;
    int nfb = (total + 255) / 256;

    if (fast) {
        int rwh = (nwords + NRH - 1) / NRH;
        hist_kernel<<<dim3(NCHUNK, 2, NRH), 512, 0, stream>>>(
            src, dst, partial_in, partial_out, n_edges, nwords, epb, rwh);
        dnr_kernel<<<nb1024, 512, 0, stream>>>(partial_in, partial_out, deg_in, norm,
                                               bsum, nwords, n_nodes);
        prep_kernel<<<nfb + 32, 256, 0, stream>>>(feat, norm, featn, total, W, wt, nfb);
        scan_final2_kernel<<<nb1024, 1024, 0, stream>>>(deg_in, bsum, start,
                                                        n_nodes, nb1024);
        int rwf = (nwords + NRF - 1) / NRF;
        fill3_kernel<<<NCHUNK * NRF, 512, 0, stream>>>(src, dst, partial_out, start,
                                                       csr_src, n_edges, nwords, epb, rwf);
        gathergemm_kernel<<<(n_nodes + GG_NODES - 1) / GG_NODES, 256, 0, stream>>>(
            featn, csr_src, start, deg_in, (const ushort*)wt, bias, (float*)d_out, n_nodes);
    } else {
        hipMemsetAsync(deg_in, 0, 2 * (size_t)n_nodes * sizeof(int), stream);
        deg_kernel<<<(n_edges + 255) / 256, 256, 0, stream>>>(src, dst, deg_out, deg_in, n_edges);
        norm_kernel<<<(n_nodes + 255) / 256, 256, 0, stream>>>(deg_out, deg_in, norm, n_nodes);
        prep_kernel<<<nfb + 32, 256, 0, stream>>>(feat, norm, featn, total, W, wt, nfb);
        int nb = (n_nodes + 1023) / 1024;
        scan_sum_kernel<<<nb, 1024, 0, stream>>>(deg_in, bsum, n_nodes);
        scan_bsum_kernel<<<1, 1024, 0, stream>>>(bsum, nb);
        scan_final_kernel<<<nb, 1024, 0, stream>>>(deg_in, bsum, start, cursor, n_nodes);
        fill_kernel<<<(n_edges + 255) / 256, 256, 0, stream>>>(src, dst, cursor, csr_src, n_edges);
        gather_kernel<<<(n_nodes * 64 + 255) / 256, 256, 0, stream>>>(featn, csr_src, start,
                                                                      deg_in, rst_h, n_nodes);
        gemm_mfma_kernel<<<(n_nodes + 63) / 64, 256, 0, stream>>>((const ushort*)rst_h,
                                                                  (const ushort*)wt, bias,
                                                                  (float*)d_out, n_nodes);
    }
}

// Round 14
// 93.736 us; speedup vs baseline: 1.6329x; 1.2662x over previous
//
#include <hip/hip_runtime.h>

#define NF 128
#define NCHUNK 32          // edge chunks
#define NRH 4              // hist node-range splits (LDS 25KB)
#define NRF 8              // fill node-range splits (LDS 12.5KB)
#define NNW_MAX 25088      // max packed u16-pair words; n_nodes <= 50176
#define RWH_MAX ((NNW_MAX + NRH - 1) / NRH)
#define RWF_MAX ((NNW_MAX + NRF - 1) / NRF)
#define GG_NODES 16        // nodes per fused gather+gemm block (finer for balance)

typedef __attribute__((ext_vector_type(8))) short short8;   // 8 x bf16
typedef __attribute__((ext_vector_type(4))) float f32x4;
typedef unsigned int uint;
typedef unsigned short ushort;

__device__ __forceinline__ ushort f2bf(float f) {
    uint u = __float_as_uint(f);
    uint r = (u + 0x7fffu + ((u >> 16) & 1u)) >> 16;
    return (ushort)r;
}
__device__ __forceinline__ float bflo(uint v) { return __uint_as_float(v << 16); }
__device__ __forceinline__ float bfhi(uint v) { return __uint_as_float(v & 0xffff0000u); }

// ---------------------------------------------------------------------------
// K1: range-split LDS degree histograms (no global atomics). 1024 threads:
// halves the serial edge loop vs 512 (16 waves/CU hide LDS-atomic latency).
// ---------------------------------------------------------------------------
__global__ __launch_bounds__(1024) void hist_kernel(const int* __restrict__ src,
                                                    const int* __restrict__ dst,
                                                    uint* __restrict__ partial_in,
                                                    uint* __restrict__ partial_out,
                                                    int n_edges, int nwords, int epb, int rw) {
    __shared__ uint h[RWH_MAX];
    int wbeg = blockIdx.z * rw;
    int wend = min(wbeg + rw, nwords);
    int nw = wend - wbeg;
    for (int w = threadIdx.x; w < nw; w += 1024) h[w] = 0;
    __syncthreads();
    const int* idx = blockIdx.y ? src : dst;
    int ebeg = blockIdx.x * epb;
    int eend = min(ebeg + epb, n_edges);
    int nodelo = wbeg * 2, nodehi = wend * 2;
    for (int e = ebeg + (int)threadIdx.x; e < eend; e += 1024) {
        int node = idx[e];
        if (node >= nodelo && node < nodehi)
            atomicAdd(&h[(node >> 1) - wbeg], 1u << ((node & 1) * 16));
    }
    __syncthreads();
    uint* p = (blockIdx.y ? partial_out : partial_in) + (size_t)blockIdx.x * nwords + wbeg;
    for (int w = threadIdx.x; w < nw; w += 1024) p[w] = h[w];
}

// ---------------------------------------------------------------------------
// K2: partials -> deg_in[], norm[], rel[c][w] in-place, bsum[b].
// ---------------------------------------------------------------------------
__global__ __launch_bounds__(512) void dnr_kernel(const uint* __restrict__ partial_in,
                                                  uint* __restrict__ partial_out,
                                                  int* __restrict__ deg_in,
                                                  float* __restrict__ norm,
                                                  int* __restrict__ bsum,
                                                  int nwords, int n) {
    int w = blockIdx.x * 512 + (int)threadIdx.x;
    uint si0 = 0, si1 = 0, so0 = 0, so1 = 0;
    if (w < nwords) {
        for (int c = 0; c < NCHUNK; ++c) {
            uint vi = partial_in[(size_t)c * nwords + w];
            uint vo = partial_out[(size_t)c * nwords + w];
            partial_out[(size_t)c * nwords + w] = si0 | (si1 << 16);   // rel
            si0 += vi & 0xffffu; si1 += vi >> 16;
            so0 += vo & 0xffffu; so1 += vo >> 16;
        }
        int n0 = 2 * w, n1 = 2 * w + 1;
        {
            uint di = si0 < 1u ? 1u : si0, dv = so0 < 1u ? 1u : so0;
            deg_in[n0] = (int)si0;
            norm[n0] = 1.0f / sqrtf((float)di * (float)dv);
        }
        if (n1 < n) {
            uint di = si1 < 1u ? 1u : si1, dv = so1 < 1u ? 1u : so1;
            deg_in[n1] = (int)si1;
            norm[n1] = 1.0f / sqrtf((float)di * (float)dv);
        }
    }
    int v = (int)(si0 + si1);
#pragma unroll
    for (int off = 32; off >= 1; off >>= 1) v += __shfl_down(v, off, 64);
    __shared__ int wsum[8];
    int wave = threadIdx.x >> 6, lane = threadIdx.x & 63;
    if (lane == 0) wsum[wave] = v;
    __syncthreads();
    if (threadIdx.x == 0) {
        int s = 0;
#pragma unroll
        for (int k = 0; k < 8; ++k) s += wsum[k];
        bsum[blockIdx.x] = s;
    }
}

// ---------------------------------------------------------------------------
// K3 (prepscan): role-split 1024-thr blocks — [0,nfb4): featn conversion,
// [nfb4, nfb4+8): W^T bf16, [nfb4+8, nfb4+8+nb): scan_final2. Every role
// keeps its full parallelism (R12 lesson: never serialize the 25.6MB pass).
// ---------------------------------------------------------------------------
__global__ __launch_bounds__(1024) void prepscan_kernel(const float* __restrict__ feat,
                                                        const float* __restrict__ norm,
                                                        uint* __restrict__ featn, int total,
                                                        const float* __restrict__ W,
                                                        uint* __restrict__ wt,
                                                        const int* __restrict__ deg,
                                                        const int* __restrict__ bsum,
                                                        int* __restrict__ start,
                                                        int n, int nb, int nfb4) {
    int bid = (int)blockIdx.x;
    if (bid < nfb4) {                       // featn
        int idx = bid * 1024 + (int)threadIdx.x;
        if (idx < total) {
            int node = idx >> 6;
            float nv = norm[node];
            float2 v = ((const float2*)feat)[idx];
            featn[idx] = (uint)f2bf(v.x * nv) | ((uint)f2bf(v.y * nv) << 16);
        }
        return;
    }
    if (bid < nfb4 + 8) {                   // wt
        int idx = (bid - nfb4) * 1024 + (int)threadIdx.x;
        if (idx < NF * NF / 2) {
            int nrow = idx >> 6;
            int k2 = idx & 63;
            float a = W[(2 * k2) * NF + nrow];
            float b = W[(2 * k2 + 1) * NF + nrow];
            wt[idx] = (uint)f2bf(a) | ((uint)f2bf(b) << 16);
        }
        return;
    }
    // scan_final2 role
    int b = bid - nfb4 - 8;
    if (b >= nb) return;
    __shared__ int ws[16];
    __shared__ int wo[16];
    __shared__ int bpre_s;
    int i = b * 1024 + (int)threadIdx.x;
    int v = (i < n) ? deg[i] : 0;
    int lane = threadIdx.x & 63, wv = threadIdx.x >> 6;
    int incl = v;
#pragma unroll
    for (int off = 1; off < 64; off <<= 1) {
        int t = __shfl_up(incl, off, 64);
        if (lane >= off) incl += t;
    }
    if (lane == 63) ws[wv] = incl;
    if (threadIdx.x < 64) {
        int bb = ((int)threadIdx.x < nb) ? bsum[threadIdx.x] : 0;
        int bi = bb;
#pragma unroll
        for (int off = 1; off < 64; off <<= 1) {
            int t = __shfl_up(bi, off, 64);
            if (lane >= off) bi += t;
        }
        int bex = bi - bb;
        int mine = __shfl(bex, b, 64);
        if (threadIdx.x == 0) bpre_s = mine;
    }
    __syncthreads();
    if (threadIdx.x == 0) {
        int s = 0;
#pragma unroll
        for (int k = 0; k < 16; ++k) { wo[k] = s; s += ws[k]; }
    }
    __syncthreads();
    if (i < n) start[i] = incl - v + wo[wv] + bpre_s;
}

// ---------------------------------------------------------------------------
// K4: range-split counting-sort CSR fill — zero global atomics. 1024 thr.
// bid%8 = range -> same csr slice written from one XCD (write coalescing).
// ---------------------------------------------------------------------------
__global__ __launch_bounds__(1024) void fill3_kernel(const int* __restrict__ src,
                                                     const int* __restrict__ dst,
                                                     const uint* __restrict__ rel,
                                                     const int* __restrict__ start,
                                                     int* __restrict__ csr_src,
                                                     int n_edges, int nwords, int epb, int rwf) {
    __shared__ uint cur[RWF_MAX];
    int c = blockIdx.x >> 3;          // NRF==8
    int r = blockIdx.x & 7;
    int wbeg = r * rwf;
    int wend = min(wbeg + rwf, nwords);
    int nw = wend - wbeg;
    for (int w = threadIdx.x; w < nw; w += 1024) cur[w] = 0;
    __syncthreads();
    const uint* relc = rel + (size_t)c * nwords;
    int ebeg = c * epb;
    int eend = min(ebeg + epb, n_edges);
    int nodelo = wbeg * 2, nodehi = wend * 2;
    for (int e = ebeg + (int)threadIdx.x; e < eend; e += 1024) {
        int d = dst[e];
        if (d >= nodelo && d < nodehi) {
            int sh = (d & 1) * 16;
            uint old = atomicAdd(&cur[(d >> 1) - wbeg], 1u << sh);
            uint rank = (old >> sh) & 0xffffu;
            uint relv = (relc[d >> 1] >> sh) & 0xffffu;
            int pos = start[d] + (int)(relv + rank);
            csr_src[pos] = src[e];
        }
    }
}

// ---------------------------------------------------------------------------
// K5: FUSED gather+gemm, GG_NODES=16, 128 thr / 2 waves. Phase 1: wave does
// 8 nodes via 4 passes of 2-node pairs (half-wave x uint2 = 256B row),
// unroll-8 => 16 rows in flight/wave. Phase 2: wave w = all 16 rows x
// col-tiles w*4..w*4+4. 3136 blocks for cross-CU balance.
// ---------------------------------------------------------------------------
__global__ __launch_bounds__(128) void gathergemm_kernel(const uint* __restrict__ featn,
                                                         const int* __restrict__ csr_src,
                                                         const int* __restrict__ start,
                                                         const int* __restrict__ deg,
                                                         const ushort* __restrict__ wt_h,
                                                         const float* __restrict__ bias,
                                                         float* __restrict__ out,
                                                         int n_nodes) {
    __shared__ uint rstl[GG_NODES][68];
    int wave = threadIdx.x >> 6;      // 0..1
    int lane = threadIdx.x & 63;
    int base = blockIdx.x * GG_NODES;
    if (base >= n_nodes) return;
    int half = lane >> 5;
    int hl   = lane & 31;

    // ---- phase 1: gather, 2 nodes per wave-pass, 4 passes ----
    for (int p = 0; p < 4; ++p) {
        int node = base + wave * 8 + p * 2 + half;
        int beg = 0, dg = 0;
        if (node < n_nodes) { beg = start[node]; dg = deg[node]; }
        const uint2* fp = (const uint2*)featn;   // row = 32 uint2
        float a0x = 0.f, a0y = 0.f, a1x = 0.f, a1y = 0.f;
        float b0x = 0.f, b0y = 0.f, b1x = 0.f, b1y = 0.f;
        int i = 0;
        for (; i + 7 < dg; i += 8) {
            int s0 = csr_src[beg + i];
            int s1 = csr_src[beg + i + 1];
            int s2 = csr_src[beg + i + 2];
            int s3 = csr_src[beg + i + 3];
            int s4 = csr_src[beg + i + 4];
            int s5 = csr_src[beg + i + 5];
            int s6 = csr_src[beg + i + 6];
            int s7 = csr_src[beg + i + 7];
            uint2 v0 = fp[(size_t)s0 * 32 + hl];
            uint2 v1 = fp[(size_t)s1 * 32 + hl];
            uint2 v2 = fp[(size_t)s2 * 32 + hl];
            uint2 v3 = fp[(size_t)s3 * 32 + hl];
            uint2 v4 = fp[(size_t)s4 * 32 + hl];
            uint2 v5 = fp[(size_t)s5 * 32 + hl];
            uint2 v6 = fp[(size_t)s6 * 32 + hl];
            uint2 v7 = fp[(size_t)s7 * 32 + hl];
            a0x += bflo(v0.x); a0y += bfhi(v0.x); a1x += bflo(v0.y); a1y += bfhi(v0.y);
            b0x += bflo(v1.x); b0y += bfhi(v1.x); b1x += bflo(v1.y); b1y += bfhi(v1.y);
            a0x += bflo(v2.x); a0y += bfhi(v2.x); a1x += bflo(v2.y); a1y += bfhi(v2.y);
            b0x += bflo(v3.x); b0y += bfhi(v3.x); b1x += bflo(v3.y); b1y += bfhi(v3.y);
            a0x += bflo(v4.x); a0y += bfhi(v4.x); a1x += bflo(v4.y); a1y += bfhi(v4.y);
            b0x += bflo(v5.x); b0y += bfhi(v5.x); b1x += bflo(v5.y); b1y += bfhi(v5.y);
            a0x += bflo(v6.x); a0y += bfhi(v6.x); a1x += bflo(v6.y); a1y += bfhi(v6.y);
            b0x += bflo(v7.x); b0y += bfhi(v7.x); b1x += bflo(v7.y); b1y += bfhi(v7.y);
        }
        for (; i + 1 < dg; i += 2) {
            int s0 = csr_src[beg + i];
            int s1 = csr_src[beg + i + 1];
            uint2 v0 = fp[(size_t)s0 * 32 + hl];
            uint2 v1 = fp[(size_t)s1 * 32 + hl];
            a0x += bflo(v0.x); a0y += bfhi(v0.x); a1x += bflo(v0.y); a1y += bfhi(v0.y);
            b0x += bflo(v1.x); b0y += bfhi(v1.x); b1x += bflo(v1.y); b1y += bfhi(v1.y);
        }
        if (i < dg) {
            int s = csr_src[beg + i];
            uint2 v = fp[(size_t)s * 32 + hl];
            a0x += bflo(v.x); a0y += bfhi(v.x); a1x += bflo(v.y); a1y += bfhi(v.y);
        }
        float r0x = a0x + b0x, r0y = a0y + b0y;
        float r1x = a1x + b1x, r1y = a1y + b1y;
        uint w0 = (uint)f2bf(r0x) | ((uint)f2bf(r0y) << 16);
        uint w1 = (uint)f2bf(r1x) | ((uint)f2bf(r1y) << 16);
        *(uint2*)&rstl[wave * 8 + p * 2 + half][hl * 2] = make_uint2(w0, w1);
    }
    __syncthreads();

    // ---- phase 2: MFMA. wave w -> all 16 rows, col-tiles w*4 .. w*4+4 ----
    int l16 = lane & 15, lq = lane >> 4;
    int nt0 = wave * 4;

    short8 a[4];
#pragma unroll
    for (int kt = 0; kt < 4; ++kt)
        a[kt] = *(const short8*)&rstl[l16][kt * 16 + lq * 4];

#pragma unroll
    for (int t = 0; t < 4; ++t) {
        int nt = nt0 + t;
        f32x4 acc = {0.0f, 0.0f, 0.0f, 0.0f};
        const ushort* bp = wt_h + (size_t)(nt * 16 + l16) * NF + lq * 8;
#pragma unroll
        for (int kt = 0; kt < 4; ++kt) {
            short8 b = *(const short8*)(bp + kt * 32);
            acc = __builtin_amdgcn_mfma_f32_16x16x32_bf16(a[kt], b, acc, 0, 0, 0);
        }
        int col = nt * 16 + l16;
        float bv = bias[col];
#pragma unroll
        for (int r = 0; r < 4; ++r) {
            int orow = base + lq * 4 + r;
            if (orow < n_nodes) {
                float v = acc[r] + bv;
                out[(size_t)orow * NF + col] = v > 0.0f ? v : 0.0f;
            }
        }
    }
}

// ======================= fallback path (robustness) =========================
__global__ __launch_bounds__(256) void deg_kernel(const int* __restrict__ src,
                                                  const int* __restrict__ dst,
                                                  int* __restrict__ deg_out,
                                                  int* __restrict__ deg_in,
                                                  int n_edges) {
    int i = blockIdx.x * 256 + threadIdx.x;
    if (i < n_edges) {
        atomicAdd(&deg_out[src[i]], 1);
        atomicAdd(&deg_in[dst[i]], 1);
    }
}
__global__ __launch_bounds__(256) void norm_kernel(const int* __restrict__ deg_out,
                                                   const int* __restrict__ deg_in,
                                                   float* __restrict__ norm, int n) {
    int i = blockIdx.x * 256 + threadIdx.x;
    if (i < n) {
        int dov = deg_out[i]; if (dov < 1) dov = 1;
        int div_ = deg_in[i]; if (div_ < 1) div_ = 1;
        norm[i] = 1.0f / sqrtf((float)dov * (float)div_);
    }
}
__global__ __launch_bounds__(256) void prep_kernel(const float* __restrict__ feat,
                                                   const float* __restrict__ norm,
                                                   uint* __restrict__ featn, int total,
                                                   const float* __restrict__ W,
                                                   uint* __restrict__ wt, int nfb) {
    if ((int)blockIdx.x < nfb) {
        int idx = blockIdx.x * 256 + threadIdx.x;
        if (idx >= total) return;
        int node = idx >> 6;
        float nv = norm[node];
        float2 v = ((const float2*)feat)[idx];
        featn[idx] = (uint)f2bf(v.x * nv) | ((uint)f2bf(v.y * nv) << 16);
    } else {
        int idx = (blockIdx.x - nfb) * 256 + threadIdx.x;
        if (idx >= NF * NF / 2) return;
        int nrow = idx >> 6;
        int k2 = idx & 63;
        float a = W[(2 * k2) * NF + nrow];
        float b = W[(2 * k2 + 1) * NF + nrow];
        wt[idx] = (uint)f2bf(a) | ((uint)f2bf(b) << 16);
    }
}
__global__ __launch_bounds__(1024) void scan_sum_kernel(const int* __restrict__ deg,
                                                        int* __restrict__ bsum, int n) {
    int i = blockIdx.x * 1024 + threadIdx.x;
    int v = (i < n) ? deg[i] : 0;
#pragma unroll
    for (int off = 32; off >= 1; off >>= 1) v += __shfl_down(v, off, 64);
    __shared__ int ws[16];
    int wv = threadIdx.x >> 6, lane = threadIdx.x & 63;
    if (lane == 0) ws[wv] = v;
    __syncthreads();
    if (threadIdx.x == 0) {
        int s = 0;
#pragma unroll
        for (int k = 0; k < 16; ++k) s += ws[k];
        bsum[blockIdx.x] = s;
    }
}
__global__ __launch_bounds__(1024) void scan_bsum_kernel(int* __restrict__ bsum, int nb) {
    __shared__ int s[1024];
    int v = (threadIdx.x < (unsigned)nb) ? bsum[threadIdx.x] : 0;
    s[threadIdx.x] = v;
    __syncthreads();
    for (int off = 1; off < 1024; off <<= 1) {
        int t = (threadIdx.x >= (unsigned)off) ? s[threadIdx.x - off] : 0;
        __syncthreads();
        s[threadIdx.x] += t;
        __syncthreads();
    }
    if (threadIdx.x < (unsigned)nb) bsum[threadIdx.x] = s[threadIdx.x] - v;
}
__global__ __launch_bounds__(1024) void scan_final_kernel(const int* __restrict__ deg,
                                                          const int* __restrict__ bsum,
                                                          int* __restrict__ start,
                                                          int* __restrict__ cursor, int n) {
    int i = blockIdx.x * 1024 + threadIdx.x;
    int v = (i < n) ? deg[i] : 0;
    int lane = threadIdx.x & 63, wv = threadIdx.x >> 6;
    int incl = v;
#pragma unroll
    for (int off = 1; off < 64; off <<= 1) {
        int t = __shfl_up(incl, off, 64);
        if (lane >= off) incl += t;
    }
    __shared__ int ws[16];
    __shared__ int wo[16];
    if (lane == 63) ws[wv] = incl;
    __syncthreads();
    if (threadIdx.x == 0) {
        int s = 0;
#pragma unroll
        for (int k = 0; k < 16; ++k) { wo[k] = s; s += ws[k]; }
    }
    __syncthreads();
    int excl = incl - v + wo[wv] + bsum[blockIdx.x];
    if (i < n) { start[i] = excl; cursor[i] = excl; }
}
__global__ __launch_bounds__(256) void fill_kernel(const int* __restrict__ src,
                                                   const int* __restrict__ dst,
                                                   int* __restrict__ cursor,
                                                   int* __restrict__ csr_src,
                                                   int n_edges) {
    int e = blockIdx.x * 256 + threadIdx.x;
    if (e < n_edges) {
        int d = dst[e];
        int pos = atomicAdd(&cursor[d], 1);
        csr_src[pos] = src[e];
    }
}
__global__ __launch_bounds__(256) void gather_kernel(const uint* __restrict__ featn,
                                                     const int* __restrict__ csr_src,
                                                     const int* __restrict__ start,
                                                     const int* __restrict__ deg,
                                                     uint* __restrict__ rst_h,
                                                     int n_nodes) {
    int wid  = (blockIdx.x * 256 + threadIdx.x) >> 6;
    int lane = threadIdx.x & 63;
    if (wid >= n_nodes) return;
    int beg = start[wid];
    int end = beg + deg[wid];
    float ax = 0.f, ay = 0.f;
    for (int i = beg; i < end; ++i) {
        int s = csr_src[i];
        uint v = featn[(size_t)s * 64 + lane];
        ax += bflo(v); ay += bfhi(v);
    }
    rst_h[(size_t)wid * 64 + lane] = (uint)f2bf(ax) | ((uint)f2bf(ay) << 16);
}
__global__ __launch_bounds__(256) void gemm_mfma_kernel(const ushort* __restrict__ rst_h,
                                                        const ushort* __restrict__ wt_h,
                                                        const float* __restrict__ bias,
                                                        float* __restrict__ out,
                                                        int n_nodes) {
    int wave = threadIdx.x >> 6;
    int lane = threadIdx.x & 63;
    int row0 = blockIdx.x * 64 + wave * 16;
    if (row0 >= n_nodes) return;
    int l16 = lane & 15, lq = lane >> 4;
    short8 a[4];
    const ushort* ap = rst_h + (size_t)(row0 + l16) * NF + lq * 8;
#pragma unroll
    for (int kt = 0; kt < 4; ++kt) a[kt] = *(const short8*)(ap + kt * 32);
#pragma unroll
    for (int nt = 0; nt < 8; ++nt) {
        f32x4 acc = {0.0f, 0.0f, 0.0f, 0.0f};
        const ushort* bp = wt_h + (size_t)(nt * 16 + l16) * NF + lq * 8;
#pragma unroll
        for (int kt = 0; kt < 4; ++kt) {
            short8 b = *(const short8*)(bp + kt * 32);
            acc = __builtin_amdgcn_mfma_f32_16x16x32_bf16(a[kt], b, acc, 0, 0, 0);
        }
        int col = nt * 16 + l16;
        float bv = bias[col];
#pragma unroll
        for (int r = 0; r < 4; ++r) {
            int orow = row0 + lq * 4 + r;
            if (orow < n_nodes) {
                float v = acc[r] + bv;
                out[(size_t)orow * NF + col] = v > 0.0f ? v : 0.0f;
            }
        }
    }
}
// ===========================================================================

extern "C" void kernel_launch(void* const* d_in, const int* in_sizes, int n_in,
                              void* d_out, int out_size, void* d_ws, size_t ws_size,
                              hipStream_t stream) {
    const float* feat = (const float*)d_in[0];
    const float* W    = (const float*)d_in[1];
    const float* bias = (const float*)d_in[2];
    const int*   src  = (const int*)d_in[3];
    const int*   dst  = (const int*)d_in[4];

    int n_nodes = in_sizes[0] / NF;
    int n_edges = in_sizes[3];

    char* ws = (char*)d_ws;
    size_t row_u32 = (size_t)n_nodes * 64;
    uint*  rst_h   = (uint*)ws;
    uint*  featn   = rst_h + row_u32;
    int*   deg_in  = (int*)(featn + row_u32);
    int*   deg_out = deg_in + n_nodes;
    float* norm    = (float*)(deg_out + n_nodes);
    int*   start   = (int*)(norm + n_nodes);
    int*   cursor  = start + n_nodes;
    int*   bsum    = cursor + n_nodes;
    uint*  wt      = (uint*)(bsum + 1024);
    int*   csr_src = (int*)(wt + NF * NF / 2);
    uint*  partial_in = (uint*)(csr_src + n_edges);

    int nwords = (n_nodes + 1) / 2;
    uint* partial_out = partial_in + (size_t)NCHUNK * nwords;
    size_t need = (size_t)((char*)(partial_out + (size_t)NCHUNK * nwords) - ws);

    int epb = (n_edges + NCHUNK - 1) / NCHUNK;
    int nb1024 = (n_nodes + 1023) / 1024;
    bool fast = (nwords <= NNW_MAX) && (epb < 65536) && (nb1024 <= 64) && (need <= ws_size);

    int total = n_nodes * 64;

    if (fast) {
        int rwh = (nwords + NRH - 1) / NRH;
        hist_kernel<<<dim3(NCHUNK, 2, NRH), 1024, 0, stream>>>(
            src, dst, partial_in, partial_out, n_edges, nwords, epb, rwh);
        dnr_kernel<<<nb1024, 512, 0, stream>>>(partial_in, partial_out, deg_in, norm,
                                               bsum, nwords, n_nodes);
        int nfb4 = (total + 1023) / 1024;
        prepscan_kernel<<<nfb4 + 8 + nb1024, 1024, 0, stream>>>(
            feat, norm, featn, total, W, wt, deg_in, bsum, start, n_nodes, nb1024, nfb4);
        int rwf = (nwords + NRF - 1) / NRF;
        fill3_kernel<<<NCHUNK * NRF, 1024, 0, stream>>>(src, dst, partial_out, start,
                                                        csr_src, n_edges, nwords, epb, rwf);
        gathergemm_kernel<<<(n_nodes + GG_NODES - 1) / GG_NODES, 128, 0, stream>>>(
            featn, csr_src, start, deg_in, (const ushort*)wt, bias, (float*)d_out, n_nodes);
    } else {
        int nfb = (total + 255) / 256;
        hipMemsetAsync(deg_in, 0, 2 * (size_t)n_nodes * sizeof(int), stream);
        deg_kernel<<<(n_edges + 255) / 256, 256, 0, stream>>>(src, dst, deg_out, deg_in, n_edges);
        norm_kernel<<<(n_nodes + 255) / 256, 256, 0, stream>>>(deg_out, deg_in, norm, n_nodes);
        prep_kernel<<<nfb + 32, 256, 0, stream>>>(feat, norm, featn, total, W, wt, nfb);
        int nb = (n_nodes + 1023) / 1024;
        scan_sum_kernel<<<nb, 1024, 0, stream>>>(deg_in, bsum, n_nodes);
        scan_bsum_kernel<<<1, 1024, 0, stream>>>(bsum, nb);
        scan_final_kernel<<<nb, 1024, 0, stream>>>(deg_in, bsum, start, cursor, n_nodes);
        fill_kernel<<<(n_edges + 255) / 256, 256, 0, stream>>>(src, dst, cursor, csr_src, n_edges);
        gather_kernel<<<(n_nodes * 64 + 255) / 256, 256, 0, stream>>>(featn, csr_src, start,
                                                                      deg_in, rst_h, n_nodes);
        gemm_mfma_kernel<<<(n_nodes + 63) / 64, 256, 0, stream>>>((const ushort*)rst_h,
                                                                  (const ushort*)wt, bias,
                                                                  (float*)d_out, n_nodes);
    }
}